// Round 8
// baseline (191.986 us; speedup 1.0000x reference)
//
#include <hip/hip_runtime.h>
#include <math.h>

#define N_PTS 300000
#define NJ 80          // K joints
#define FDIM 64        // feature dim
#define VN 6890        // smpl verts
#define NROUND 9375    // 300000 / 32  (exact)
#define GRID_A 1024
#define WAVES_A (GRID_A * 4)

typedef __attribute__((ext_vector_type(8))) short short8;
typedef __attribute__((ext_vector_type(4))) float f32x4;

union Frag { uint32_t u[4]; short8 v; };

// hi-pair pack: two f32 -> one u32 of two bf16 (truncated)
__device__ __forceinline__ uint32_t packhi(float a, float b) {
  return (__float_as_uint(a) >> 16) | (__float_as_uint(b) & 0xFFFF0000u);
}
// residual-lo pair pack
__device__ __forceinline__ uint32_t packlo(float a, float b) {
  float la = a - __uint_as_float(__float_as_uint(a) & 0xFFFF0000u);
  float lb = b - __uint_as_float(__float_as_uint(b) & 0xFFFF0000u);
  return packhi(la, lb);
}

// DPP cross-lane (VALU pipe, within row-16): quad_perm xor1/xor2 + mirrors
#define DPPF(x, ctrl) __uint_as_float((uint32_t)__builtin_amdgcn_update_dpp( \
    0, (int)__float_as_uint(x), (ctrl), 0xF, 0xF, true))

// ---------------------------------------------------------------------------
// kA: barrier-free per-wave pipeline over 32-pt rounds, software-pipelined:
//   pack(round r: vv -> bf16 frags + sT stage)  [last use of vv]
//   -> issue loads(round r+stride) into vv      [HBM latency hidden under...]
//   -> GEMM1 (60 MFMA) -> DPP softmax -> GEMM2 (25 MFMA, wave-private sT)
// Epilogue: block LDS-reduce -> per-block partials (kR reduces) or atomics.
// ---------------------------------------------------------------------------
__global__ __launch_bounds__(256, 2) void kA(
    const float* __restrict__ xyz, const float* __restrict__ feature,
    const float* __restrict__ centers, float* __restrict__ jacc,
    float* __restrict__ part)
{
  __shared__ ushort sClo[NJ][72];      // centers residual-lo bf16
  __shared__ ushort sT[4][NJ][36];     // per-wave D^T tile [dim][pt32]; rows 68..79 zero

  const int tid = threadIdx.x;
  const int w = tid >> 6;        // wave 0..3
  const int l = tid & 63;
  const int i = l & 15;          // lane-in-16
  const int g = l >> 4;          // quarter-group 0..3

  // zero sT (rows >= 68 must stay zero; rest rewritten every round)
  for (int idx = tid; idx < 4 * NJ * 36; idx += 256) ((ushort*)sT)[idx] = 0;
  // centers residual-lo
  for (int idx = tid; idx < NJ * FDIM; idx += 256) {
    float f = centers[idx];
    float lo = f - __uint_as_float(__float_as_uint(f) & 0xFFFF0000u);
    sClo[idx >> 6][idx & 63] = (ushort)(__float_as_uint(lo) >> 16);
  }

  // centers-hi B-frags in registers + |c|^2
  Frag bh[5][2];
  float cn[5];
#pragma unroll
  for (int nt = 0; nt < 5; ++nt) {
    float s = 0.f;
#pragma unroll
    for (int ks = 0; ks < 2; ++ks) {
      const float4* cp = (const float4*)(centers + (size_t)(i + 16*nt) * FDIM + 32*ks + 8*g);
      float4 v0 = cp[0], v1 = cp[1];
      bh[nt][ks].u[0] = packhi(v0.x, v0.y);
      bh[nt][ks].u[1] = packhi(v0.z, v0.w);
      bh[nt][ks].u[2] = packhi(v1.x, v1.y);
      bh[nt][ks].u[3] = packhi(v1.z, v1.w);
      s += v0.x*v0.x + v0.y*v0.y + v0.z*v0.z + v0.w*v0.w
         + v1.x*v1.x + v1.y*v1.y + v1.z*v1.z + v1.w*v1.w;
    }
    s += __shfl_xor(s, 16);
    s += __shfl_xor(s, 32);
    cn[nt] = s;
  }

  f32x4 acc2[5][5];
#pragma unroll
  for (int a = 0; a < 5; ++a)
#pragma unroll
    for (int b = 0; b < 5; ++b) acc2[a][b] = (f32x4){0.f, 0.f, 0.f, 0.f};

  __syncthreads();   // sClo / sT ready

  float4 vv[2][2][2];     // [chunk][ks][half]
  float  xq[2];

#define LOADR(RD) do {                                                        \
    const int pb_ = (RD) * 32;                                                \
    _Pragma("unroll")                                                         \
    for (int c_ = 0; c_ < 2; ++c_) {                                          \
      const int pt_ = pb_ + 16*c_ + i;                                        \
      const float4* f0_ = (const float4*)(feature + (size_t)pt_ * FDIM + 8*g);\
      vv[c_][0][0] = f0_[0]; vv[c_][0][1] = f0_[1];                           \
      const float4* f1_ = (const float4*)(feature + (size_t)pt_ * FDIM + 32 + 8*g);\
      vv[c_][1][0] = f1_[0]; vv[c_][1][1] = f1_[1];                           \
      xq[c_] = (g < 3) ? xyz[(size_t)pt_ * 3 + g] : 1.0f;                     \
    }                                                                         \
  } while (0)

  int rd = blockIdx.x * 4 + w;
  if (rd < NROUND) LOADR(rd);

  while (rd < NROUND) {
    // -------- pack both chunks (consumes vv) + stage D^T --------
    Frag fh[2][2], fl[2][2];
#pragma unroll
    for (int c = 0; c < 2; ++c) {
#pragma unroll
      for (int ks = 0; ks < 2; ++ks) {
        float4 v0 = vv[c][ks][0], v1 = vv[c][ks][1];
        fh[c][ks].u[0] = packhi(v0.x, v0.y); fh[c][ks].u[1] = packhi(v0.z, v0.w);
        fh[c][ks].u[2] = packhi(v1.x, v1.y); fh[c][ks].u[3] = packhi(v1.z, v1.w);
        fl[c][ks].u[0] = packlo(v0.x, v0.y); fl[c][ks].u[1] = packlo(v0.z, v0.w);
        fl[c][ks].u[2] = packlo(v1.x, v1.y); fl[c][ks].u[3] = packlo(v1.z, v1.w);
        const int d0 = 32*ks + 8*g, pcol = 16*c + i;
        sT[w][d0+0][pcol] = (ushort)(fh[c][ks].u[0] & 0xFFFFu);
        sT[w][d0+1][pcol] = (ushort)(fh[c][ks].u[0] >> 16);
        sT[w][d0+2][pcol] = (ushort)(fh[c][ks].u[1] & 0xFFFFu);
        sT[w][d0+3][pcol] = (ushort)(fh[c][ks].u[1] >> 16);
        sT[w][d0+4][pcol] = (ushort)(fh[c][ks].u[2] & 0xFFFFu);
        sT[w][d0+5][pcol] = (ushort)(fh[c][ks].u[2] >> 16);
        sT[w][d0+6][pcol] = (ushort)(fh[c][ks].u[3] & 0xFFFFu);
        sT[w][d0+7][pcol] = (ushort)(fh[c][ks].u[3] >> 16);
      }
      sT[w][64 + g][16*c + i] =
          (g < 3) ? (ushort)(__float_as_uint(xq[c]) >> 16) : (ushort)0x3F80;
    }

    // -------- prefetch next round (overwrites vv after last use) --------
    const int rdn = rd + WAVES_A;
    if (rdn < NROUND) LOADR(rdn);

    // -------- GEMM1: logits for both chunks --------
    f32x4 acc1[2][5];
#pragma unroll
    for (int c = 0; c < 2; ++c)
#pragma unroll
      for (int nt = 0; nt < 5; ++nt) acc1[c][nt] = (f32x4){0.f, 0.f, 0.f, 0.f};

#pragma unroll
    for (int c = 0; c < 2; ++c)
#pragma unroll
      for (int ks = 0; ks < 2; ++ks) {
#pragma unroll
        for (int nt = 0; nt < 5; ++nt) {
          Frag bl;
          *(uint4*)bl.u = *(const uint4*)&sClo[i + 16*nt][32*ks + 8*g];
          acc1[c][nt] = __builtin_amdgcn_mfma_f32_16x16x32_bf16(fh[c][ks].v, bh[nt][ks].v, acc1[c][nt], 0, 0, 0);
          acc1[c][nt] = __builtin_amdgcn_mfma_f32_16x16x32_bf16(fl[c][ks].v, bh[nt][ks].v, acc1[c][nt], 0, 0, 0);
          acc1[c][nt] = __builtin_amdgcn_mfma_f32_16x16x32_bf16(fh[c][ks].v, bl.v,         acc1[c][nt], 0, 0, 0);
        }
      }

    // -------- softmax (DPP butterflies over the 16 i-lanes) --------
    Frag pA[5];
#pragma unroll
    for (int c = 0; c < 2; ++c) {
      f32x4 e5[5];
#pragma unroll
      for (int nt = 0; nt < 5; ++nt) {
#pragma unroll
        for (int r = 0; r < 4; ++r) e5[nt][r] = 2.f * acc1[c][nt][r] - cn[nt];
      }
      float rs[4];
#pragma unroll
      for (int r = 0; r < 4; ++r) {
        float m = e5[0][r];
#pragma unroll
        for (int nt = 1; nt < 5; ++nt) m = fmaxf(m, e5[nt][r]);
        m = fmaxf(m, DPPF(m, 0xB1));    // quad_perm xor1
        m = fmaxf(m, DPPF(m, 0x4E));    // quad_perm xor2
        m = fmaxf(m, DPPF(m, 0x141));   // row_half_mirror
        m = fmaxf(m, DPPF(m, 0x140));   // row_mirror
        float s = 0.f;
#pragma unroll
        for (int nt = 0; nt < 5; ++nt) {
          float e = __expf(e5[nt][r] - m);
          e5[nt][r] = e;
          s += e;
        }
        s += DPPF(s, 0xB1);
        s += DPPF(s, 0x4E);
        s += DPPF(s, 0x141);
        s += DPPF(s, 0x140);
        rs[r] = __builtin_amdgcn_rcpf(s);
      }
#pragma unroll
      for (int nt = 0; nt < 5; ++nt) {
        pA[nt].u[2*c + 0] = packhi(e5[nt][0] * rs[0], e5[nt][1] * rs[1]);
        pA[nt].u[2*c + 1] = packhi(e5[nt][2] * rs[2], e5[nt][3] * rs[3]);
      }
    } // chunk

    // -------- GEMM2: jacc[joint][col] += P * D (wave-private T) --------
#pragma unroll
    for (int ct = 0; ct < 5; ++ct) {
      Frag B;
      *(uint2*)&B.u[0] = *(const uint2*)&sT[w][16*ct + i][4*g];
      *(uint2*)&B.u[2] = *(const uint2*)&sT[w][16*ct + i][16 + 4*g];
#pragma unroll
      for (int nt = 0; nt < 5; ++nt)
        acc2[nt][ct] = __builtin_amdgcn_mfma_f32_16x16x32_bf16(pA[nt].v, B.v, acc2[nt][ct], 0, 0, 0);
    }
    rd = rdn;
  } // rounds

  // -------- epilogue: block-reduce in LDS (alias over sT), then store ------
  __syncthreads();
  float* sJ = (float*)&sT[0][0][0];    // 23040B >= 5440*4B
  for (int idx = tid; idx < 5440; idx += 256) sJ[idx] = 0.f;
  __syncthreads();
#pragma unroll
  for (int ww = 0; ww < 4; ++ww) {
    if (w == ww) {
#pragma unroll
      for (int nt = 0; nt < 5; ++nt)
#pragma unroll
        for (int ct = 0; ct < 5; ++ct) {
          if (ct < 4 || i < 4) {
            const int col = 16*ct + i;
#pragma unroll
            for (int r = 0; r < 4; ++r)
              sJ[(16*nt + 4*g + r) * 68 + col] += acc2[nt][ct][r];
          }
        }
    }
    __syncthreads();
  }
  if (part) {
    for (int idx = tid; idx < 5440; idx += 256)
      part[(size_t)blockIdx.x * 5440 + idx] = sJ[idx];
  } else {
    for (int idx = tid; idx < 5440; idx += 256)
      atomicAdd(&jacc[idx], sJ[idx]);
  }
#undef LOADR
}

// ---------------------------------------------------------------------------
// kR: jacc[t] += sum over 1024 block partials (16 slices x 64)
// ---------------------------------------------------------------------------
__global__ __launch_bounds__(256) void kR(const float* __restrict__ part,
                                          float* __restrict__ jacc)
{
  const int bx = blockIdx.x;
  const int cg = bx % 22, sl = bx / 22;
  const int t = cg * 256 + threadIdx.x;
  if (t >= 5440) return;
  const int b0 = sl * (GRID_A / 16);
  float s0 = 0.f, s1 = 0.f, s2 = 0.f, s3 = 0.f;
  for (int b = b0; b < b0 + GRID_A / 16; b += 4) {
    s0 += part[(size_t)(b+0) * 5440 + t];
    s1 += part[(size_t)(b+1) * 5440 + t];
    s2 += part[(size_t)(b+2) * 5440 + t];
    s3 += part[(size_t)(b+3) * 5440 + t];
  }
  atomicAdd(&jacc[t], (s0 + s1) + (s2 + s3));
}

// ---------------------------------------------------------------------------
// kB: one block (1 wave) per joint: finalize, lo/hi, argmin, full MLP chain
// ---------------------------------------------------------------------------
__global__ __launch_bounds__(64) void kB(
    const float* __restrict__ jacc, const float* __restrict__ smpl,
    const float* __restrict__ sw, const float* __restrict__ bpf,
    const float* __restrict__ w_body, const float* __restrict__ b_body,
    const float* __restrict__ w_pos1, const float* __restrict__ b_pos1,
    const float* __restrict__ w_pos2, const float* __restrict__ b_pos2,
    const float* __restrict__ w_rot,  const float* __restrict__ b_rot,
    const float* __restrict__ w_trans,const float* __restrict__ b_trans,
    float* __restrict__ jpack, float* __restrict__ qpack,
    float* __restrict__ tpack)
{
  const int k = blockIdx.x;
  const int l = threadIdx.x;
  __shared__ float gin[128];
  __shared__ float in2[67];
  __shared__ float h2[128];
  __shared__ float g2[64];
  __shared__ float q7[8];

  const float cnt = jacc[k*68 + 67] + 1e-6f;
  gin[64 + l] = jacc[k*68 + l] / cnt;
  const float jx = jacc[k*68 + 64] / cnt;
  const float jy = jacc[k*68 + 65] / cnt;
  const float jz = jacc[k*68 + 66] / cnt;

  float lo0 = 1e30f, lo1 = 1e30f, lo2 = 1e30f;
  float hi0 = -1e30f, hi1 = -1e30f, hi2 = -1e30f;
  float best = 1e30f; int bi = 0;
  for (int v = l; v < VN; v += 64) {
    float x = smpl[v*3], y = smpl[v*3+1], z = smpl[v*3+2];
    lo0 = fminf(lo0, x); hi0 = fmaxf(hi0, x);
    lo1 = fminf(lo1, y); hi1 = fmaxf(hi1, y);
    lo2 = fminf(lo2, z); hi2 = fmaxf(hi2, z);
    float dx = x - jx, dy = y - jy, dz = z - jz;
    float d = dx*dx + dy*dy + dz*dz;
    if (d < best) { best = d; bi = v; }
  }
#pragma unroll
  for (int m = 1; m < 64; m <<= 1) {
    lo0 = fminf(lo0, __shfl_xor(lo0, m));
    lo1 = fminf(lo1, __shfl_xor(lo1, m));
    lo2 = fminf(lo2, __shfl_xor(lo2, m));
    hi0 = fmaxf(hi0, __shfl_xor(hi0, m));
    hi1 = fmaxf(hi1, __shfl_xor(hi1, m));
    hi2 = fmaxf(hi2, __shfl_xor(hi2, m));
    float d2 = __shfl_xor(best, m); int i2 = __shfl_xor(bi, m);
    if (d2 < best || (d2 == best && i2 < bi)) { best = d2; bi = i2; }
  }

  {
    float s = 0.f;
    for (int j = 0; j < 24; ++j) s += sw[bi*24 + j] * bpf[j*64 + l];
    gin[l] = s;
  }
  if (l < 3) {
    float lo = (l == 0) ? lo0 : (l == 1) ? lo1 : lo2;
    float hi = (l == 0) ? hi0 : (l == 1) ? hi1 : hi2;
    float jc = (l == 0) ? jx : (l == 1) ? jy : jz;
    in2[l] = 2.f * (jc - lo) / (hi - lo + 1e-6f) - 1.f;
  }
  __syncthreads();

  {
    float s = b_body[l];
    for (int t = 0; t < 128; ++t) s += gin[t] * w_body[t*64 + l];
    float u = 0.7978845608028654f * (s + 0.044715f * s * s * s);
    float e = __expf(2.f * u);
    float th = 1.f - 2.f / (e + 1.f);
    in2[3 + l] = 0.5f * s * (1.f + th);
  }
  __syncthreads();

#pragma unroll
  for (int half = 0; half < 2; ++half) {
    const int m = l + 64*half;
    float s = b_pos1[m];
    for (int t = 0; t < 67; ++t) s += in2[t] * w_pos1[t*128 + m];
    h2[m] = fmaxf(s, 0.f);
  }
  __syncthreads();

  {
    float s = b_pos2[l];
    for (int t = 0; t < 128; ++t) s += h2[t] * w_pos2[t*64 + l];
    g2[l] = s;
  }
  __syncthreads();

  if (l < 4) {
    float s = b_rot[l];
    for (int t = 0; t < 64; ++t) s += g2[t] * w_rot[t*4 + l];
    q7[l] = s;
  } else if (l < 7) {
    const int j = l - 4;
    float s = b_trans[j];
    for (int t = 0; t < 64; ++t) s += g2[t] * w_trans[t*3 + j];
    q7[l] = s;
  }
  __syncthreads();
  if (l == 0) {
    float q0 = q7[0], q1 = q7[1], q2 = q7[2], q3 = q7[3];
    float rn = 1.f / (sqrtf(q0*q0 + q1*q1 + q2*q2 + q3*q3) + 1e-6f);
    *(float4*)&qpack[k*4] = make_float4(q0*rn, q1*rn, q2*rn, q3*rn);
    *(float4*)&tpack[k*4] = make_float4(q7[4], q7[5], q7[6], 0.f);
    *(float4*)&jpack[k*4] = make_float4(jx, jy, jz, jx*jx + jy*jy + jz*jz);
  }
}

// ---------------------------------------------------------------------------
// kC: per-point joint softmax + quaternion blend; xyz/out staged via LDS
// ---------------------------------------------------------------------------
__global__ __launch_bounds__(256) void kC(
    const float* __restrict__ xyz, const float* __restrict__ jpack,
    const float* __restrict__ qpack, const float* __restrict__ tpack,
    float* __restrict__ out)
{
  __shared__ float4 sj[NJ], sq[NJ], st[NJ];
  __shared__ float sxy[768];
  const int tid = threadIdx.x;
  const int pbase = blockIdx.x * 256;
  const int nval = min(256, N_PTS - pbase);
  const int cnt3 = nval * 3;

  if (tid < 80)        sj[tid]       = ((const float4*)jpack)[tid];
  else if (tid < 160)  sq[tid - 80]  = ((const float4*)qpack)[tid - 80];
  else if (tid < 240)  st[tid - 160] = ((const float4*)tpack)[tid - 160];
  for (int t = tid; t < cnt3; t += 256) sxy[t] = xyz[(size_t)pbase * 3 + t];
  __syncthreads();

  const bool valid = tid < nval;
  float x0 = 0.f, x1 = 0.f, x2 = 0.f;
  if (valid) { x0 = sxy[tid*3]; x1 = sxy[tid*3+1]; x2 = sxy[tid*3+2]; }
  __syncthreads();   // all reads done before overwrite

  float lv[NJ];
  float m = -1e30f;
#pragma unroll
  for (int k = 0; k < NJ; ++k) {
    float4 j = sj[k];
    lv[k] = (2.f*(x0*j.x + x1*j.y + x2*j.z) - j.w) * 10.0f;  // 1/SIGMA
    m = fmaxf(m, lv[k]);
  }
  float s = 0.f;
  float qb0=0,qb1=0,qb2=0,qb3=0, tb0=0,tb1=0,tb2=0;
#pragma unroll
  for (int k = 0; k < NJ; ++k) {
    float e = __expf(lv[k] - m);
    s += e;
    float4 q = sq[k];
    float4 t = st[k];
    qb0 += e*q.x; qb1 += e*q.y; qb2 += e*q.z; qb3 += e*q.w;
    tb0 += e*t.x; tb1 += e*t.y; tb2 += e*t.z;
  }
  float rs = 1.f / s;
  qb0*=rs; qb1*=rs; qb2*=rs; qb3*=rs; tb0*=rs; tb1*=rs; tb2*=rs;
  float nrm = sqrtf(qb0*qb0+qb1*qb1+qb2*qb2+qb3*qb3) + 1e-6f;
  float rn = 1.f / nrm;
  float qw = qb0*rn, qx = qb1*rn, qy = qb2*rn, qz = qb3*rn;
  float t2x = 2.f*(qy*x2 - qz*x1);
  float t2y = 2.f*(qz*x0 - qx*x2);
  float t2z = 2.f*(qx*x1 - qy*x0);
  float cx = qy*t2z - qz*t2y;
  float cy = qz*t2x - qx*t2z;
  float cz = qx*t2y - qy*t2x;
  float r0 = x0 + qw*t2x + cx + tb0;
  float r1 = x1 + qw*t2y + cy + tb1;
  float r2 = x2 + qw*t2z + cz + tb2;

  if (valid) { sxy[tid*3] = r0; sxy[tid*3+1] = r1; sxy[tid*3+2] = r2; }
  __syncthreads();
  for (int t = tid; t < cnt3; t += 256) out[(size_t)pbase * 3 + t] = sxy[t];
}

// ---------------------------------------------------------------------------
extern "C" void kernel_launch(void* const* d_in, const int* in_sizes, int n_in,
                              void* d_out, int out_size, void* d_ws, size_t ws_size,
                              hipStream_t stream) {
  const float* xyz     = (const float*)d_in[0];
  const float* feature = (const float*)d_in[1];
  const float* centers = (const float*)d_in[2];
  const float* smpl    = (const float*)d_in[3];
  const float* sw      = (const float*)d_in[4];
  const float* bpf     = (const float*)d_in[5];
  const float* w_body  = (const float*)d_in[6];
  const float* b_body  = (const float*)d_in[7];
  const float* w_pos1  = (const float*)d_in[8];
  const float* b_pos1  = (const float*)d_in[9];
  const float* w_pos2  = (const float*)d_in[10];
  const float* b_pos2  = (const float*)d_in[11];
  const float* w_rot   = (const float*)d_in[12];
  const float* b_rot   = (const float*)d_in[13];
  const float* w_trans = (const float*)d_in[14];
  const float* b_trans = (const float*)d_in[15];
  float* out = (float*)d_out;

  float* ws    = (float*)d_ws;
  float* jacc  = ws;                  // 5440
  float* jpack = ws + 5440;           // 320
  float* qpack = ws + 5760;           // 320
  float* tpack = ws + 6080;           // 320
  float* part  = ws + 6400;           // GRID_A * 5440 (if it fits)

  const size_t need = (size_t)6400 + (size_t)GRID_A * 5440;
  const bool use_part = (ws_size / 4) >= need;
  float* part_arg = use_part ? part : nullptr;

  hipMemsetAsync(jacc, 0, 5440 * sizeof(float), stream);
  kA<<<dim3(GRID_A), dim3(256), 0, stream>>>(xyz, feature, centers, jacc, part_arg);
  if (use_part)
    kR<<<dim3(22 * 16), dim3(256), 0, stream>>>(part, jacc);
  kB<<<dim3(NJ), dim3(64), 0, stream>>>(jacc, smpl, sw, bpf,
                                        w_body, b_body, w_pos1, b_pos1,
                                        w_pos2, b_pos2, w_rot, b_rot,
                                        w_trans, b_trans, jpack, qpack, tpack);
  kC<<<dim3((N_PTS + 255) / 256), dim3(256), 0, stream>>>(xyz, jpack, qpack, tpack, out);
}

// Round 9
// 128.673 us; speedup vs baseline: 1.4920x; 1.4920x over previous
//
#include <hip/hip_runtime.h>
#include <math.h>

#define N_PTS 300000
#define NJ 80          // K joints
#define FDIM 64        // feature dim
#define VN 6890        // smpl verts
#define NROUND 9375    // 300000 / 32 (exact)
#define GRID_A 256
#define TOTW 1024      // GRID_A * 4 waves
#define SLOT_B 8704    // 8192 B feature + 512 B xyz per ring slot

typedef __attribute__((ext_vector_type(8))) short short8;
typedef __attribute__((ext_vector_type(4))) float f32x4;

union Frag { uint32_t u[4]; short8 v; };

__device__ __forceinline__ uint32_t packhi(float a, float b) {
  return (__float_as_uint(a) >> 16) | (__float_as_uint(b) & 0xFFFF0000u);
}
__device__ __forceinline__ uint32_t packlo(float a, float b) {
  float la = a - __uint_as_float(__float_as_uint(a) & 0xFFFF0000u);
  float lb = b - __uint_as_float(__float_as_uint(b) & 0xFFFF0000u);
  return packhi(la, lb);
}

#define DPPF(x, ctrl) __uint_as_float((uint32_t)__builtin_amdgcn_update_dpp( \
    0, (int)__float_as_uint(x), (ctrl), 0xF, 0xF, true))

__device__ __forceinline__ void gl16(const float* g, const void* l) {
  __builtin_amdgcn_global_load_lds(
      (const __attribute__((address_space(1))) void*)g,
      (__attribute__((address_space(3))) void*)l, 16, 0, 0);
}
__device__ __forceinline__ void gl4(const float* g, const void* l) {
  __builtin_amdgcn_global_load_lds(
      (const __attribute__((address_space(1))) void*)g,
      (__attribute__((address_space(3))) void*)l, 4, 0, 0);
}

// ---------------------------------------------------------------------------
// kA: barrier-free per-wave pipeline, async global->LDS staging (depth-3
// wave-private ring, counted vmcnt). Per 32-pt round:
//   A-frags read from staged fp32 tile (unit-XOR swizzled: LDS unit
//   lu = ptl*16 + j holds global unit ptl*16 + (j ^ (ptl&7))),
//   B(GEMM1) = centers hi/lo u16 LDS; 3-term MFMA -> logits -> DPP softmax
//   -> P in regs (A-frag of GEMM2, swapped-operand) -> GEMM2 B read
//   directly from the swizzled tile (bf16-hi) -> acc2[5][5] persists.
// ---------------------------------------------------------------------------
__global__ __launch_bounds__(256, 2) void kA(
    const float* __restrict__ xyz, const float* __restrict__ feature,
    const float* __restrict__ centers, float* __restrict__ jacc,
    float* __restrict__ part)
{
  __shared__ __align__(16) unsigned char ring[4][3][SLOT_B];  // 104448 B
  __shared__ ushort sChi[NJ][72];                             // 11520 B
  __shared__ ushort sClo[NJ][72];                             // 11520 B

  const int tid = threadIdx.x;
  const int w = tid >> 6;        // wave 0..3
  const int l = tid & 63;
  const int i = l & 15;          // lane-in-16
  const int g = l >> 4;          // quarter-group 0..3
  const int gw = blockIdx.x * 4 + w;

  // stage round rs into ring slot st (wave-private; 10 VMEM insts)
  auto STAGE = [&](int st, int rs) {
    const float* fb = feature + (size_t)rs * 2048;   // 32 pts x 64 dims
    unsigned char* base = &ring[w][st][0];
#pragma unroll
    for (int k = 0; k < 8; ++k) {
      const int lu = k * 64 + l;
      const int ptl = lu >> 4;
      const int gu = ptl * 16 + ((lu & 15) ^ (ptl & 7));
      gl16(fb + gu * 4, base + k * 1024);
    }
    const float* xb = xyz + (size_t)rs * 96;
#pragma unroll
    for (int k = 0; k < 2; ++k) {
      int fi = k * 64 + l; if (fi > 95) fi = 95;
      gl4(xb + fi, base + 8192 + k * 256);
    }
  };

  // prologue staging (before center init, to overlap)
  {
    int r1 = gw + TOTW; if (r1 > NROUND - 1) r1 = NROUND - 1;
    STAGE(0, gw);
    STAGE(1, r1);
  }

  // centers -> hi/lo u16 LDS
  for (int idx = tid; idx < NJ * FDIM; idx += 256) {
    float f = centers[idx];
    sChi[idx >> 6][idx & 63] = (ushort)(__float_as_uint(f) >> 16);
    float lo = f - __uint_as_float(__float_as_uint(f) & 0xFFFF0000u);
    sClo[idx >> 6][idx & 63] = (ushort)(__float_as_uint(lo) >> 16);
  }
  // |c|^2 per joint (5 per lane via shfl)
  float cn[5];
#pragma unroll
  for (int nt = 0; nt < 5; ++nt) {
    float s = 0.f;
    const float* cp = centers + (size_t)(i + 16 * nt) * FDIM + 8 * g;
#pragma unroll
    for (int e = 0; e < 8; ++e) {
      float a0 = cp[e], a1 = cp[32 + e];
      s += a0 * a0 + a1 * a1;
    }
    s += __shfl_xor(s, 16);
    s += __shfl_xor(s, 32);
    cn[nt] = s;
  }
  __syncthreads();   // sChi/sClo ready (drains prologue vmcnt too - one-time)

  f32x4 acc2[5][5];
#pragma unroll
  for (int a = 0; a < 5; ++a)
#pragma unroll
    for (int b = 0; b < 5; ++b) acc2[a][b] = (f32x4){0.f, 0.f, 0.f, 0.f};

  int s3 = 0;   // current slot = iter mod 3
  for (int r = gw; r < NROUND; r += TOTW) {
    // wait current slot ready: allow the 10 insts of the next-round batch
    asm volatile("s_waitcnt vmcnt(10)" ::: "memory");
    __builtin_amdgcn_sched_barrier(0);
    // issue round r+2 into slot (s3+2)%3 (read 2 iters ago -> safe)
    {
      int rn = r + 2 * TOTW; if (rn > NROUND - 1) rn = NROUND - 1;
      int st = s3 + 2; if (st >= 3) st -= 3;
      STAGE(st, rn);
    }
    __builtin_amdgcn_sched_barrier(0);

    const float* F = (const float*)&ring[w][s3][0];
    const float* X = (const float*)&ring[w][s3][8192];

    Frag pA[5];
#pragma unroll
    for (int c = 0; c < 2; ++c) {
      f32x4 acc1[5];
#pragma unroll
      for (int nt = 0; nt < 5; ++nt) acc1[nt] = (f32x4){0.f, 0.f, 0.f, 0.f};

      const int ptl = 16 * c + i;
      const int m = ptl & 7;
#pragma unroll
      for (int ks = 0; ks < 2; ++ks) {
        const int j = 8 * ks + 2 * g;
        float4 va = *(const float4*)(F + ptl * 64 + ((j ^ m) << 2));
        float4 vb = *(const float4*)(F + ptl * 64 + (((j + 1) ^ m) << 2));
        Frag ah, al;
        ah.u[0] = packhi(va.x, va.y); ah.u[1] = packhi(va.z, va.w);
        ah.u[2] = packhi(vb.x, vb.y); ah.u[3] = packhi(vb.z, vb.w);
        al.u[0] = packlo(va.x, va.y); al.u[1] = packlo(va.z, va.w);
        al.u[2] = packlo(vb.x, vb.y); al.u[3] = packlo(vb.z, vb.w);
#pragma unroll
        for (int nt = 0; nt < 5; ++nt) {
          Frag bh, bl;
          *(uint4*)bh.u = *(const uint4*)&sChi[i + 16 * nt][32 * ks + 8 * g];
          *(uint4*)bl.u = *(const uint4*)&sClo[i + 16 * nt][32 * ks + 8 * g];
          acc1[nt] = __builtin_amdgcn_mfma_f32_16x16x32_bf16(ah.v, bh.v, acc1[nt], 0, 0, 0);
          acc1[nt] = __builtin_amdgcn_mfma_f32_16x16x32_bf16(al.v, bh.v, acc1[nt], 0, 0, 0);
          acc1[nt] = __builtin_amdgcn_mfma_f32_16x16x32_bf16(ah.v, bl.v, acc1[nt], 0, 0, 0);
        }
      }

      // softmax over 80 joints (DPP butterflies over the 16 i-lanes)
      f32x4 e5[5];
#pragma unroll
      for (int nt = 0; nt < 5; ++nt)
#pragma unroll
        for (int rr = 0; rr < 4; ++rr) e5[nt][rr] = 2.f * acc1[nt][rr] - cn[nt];
      float rs[4];
#pragma unroll
      for (int rr = 0; rr < 4; ++rr) {
        float mm = e5[0][rr];
#pragma unroll
        for (int nt = 1; nt < 5; ++nt) mm = fmaxf(mm, e5[nt][rr]);
        mm = fmaxf(mm, DPPF(mm, 0xB1));
        mm = fmaxf(mm, DPPF(mm, 0x4E));
        mm = fmaxf(mm, DPPF(mm, 0x141));
        mm = fmaxf(mm, DPPF(mm, 0x140));
        float ss = 0.f;
#pragma unroll
        for (int nt = 0; nt < 5; ++nt) {
          float e = __expf(e5[nt][rr] - mm);
          e5[nt][rr] = e;
          ss += e;
        }
        ss += DPPF(ss, 0xB1);
        ss += DPPF(ss, 0x4E);
        ss += DPPF(ss, 0x141);
        ss += DPPF(ss, 0x140);
        rs[rr] = __builtin_amdgcn_rcpf(ss);
      }
#pragma unroll
      for (int nt = 0; nt < 5; ++nt) {
        pA[nt].u[2 * c + 0] = packhi(e5[nt][0] * rs[0], e5[nt][1] * rs[1]);
        pA[nt].u[2 * c + 1] = packhi(e5[nt][2] * rs[2], e5[nt][3] * rs[3]);
      }
    } // chunk

    // GEMM2: acc2[nt][ct] += P(joints x pts) * D(pts x dims)
#pragma unroll
    for (int ct = 0; ct < 5; ++ct) {
      Frag B;
      float x[8];
      if (ct < 4) {
        const int d = 16 * ct + i, jd = d >> 2, db = d & 3;
#pragma unroll
        for (int n = 0; n < 8; ++n) {
          const int ptl = (n < 4) ? (4 * g + n) : (16 + 4 * g + (n - 4));
          x[n] = F[ptl * 64 + ((jd ^ (ptl & 7)) << 2) + db];
        }
      } else {
#pragma unroll
        for (int n = 0; n < 8; ++n) {
          const int ptl = (n < 4) ? (4 * g + n) : (16 + 4 * g + (n - 4));
          x[n] = (i < 3) ? X[ptl * 3 + i] : (i == 3 ? 1.f : 0.f);
        }
      }
      B.u[0] = packhi(x[0], x[1]); B.u[1] = packhi(x[2], x[3]);
      B.u[2] = packhi(x[4], x[5]); B.u[3] = packhi(x[6], x[7]);
#pragma unroll
      for (int nt = 0; nt < 5; ++nt)
        acc2[nt][ct] = __builtin_amdgcn_mfma_f32_16x16x32_bf16(pA[nt].v, B.v, acc2[nt][ct], 0, 0, 0);
    }

    s3 += 1; if (s3 >= 3) s3 -= 3;
  } // rounds

  // -------- epilogue: drain staging, block-reduce in LDS, store ------------
  asm volatile("s_waitcnt vmcnt(0)" ::: "memory");
  __syncthreads();
  float* sJ = (float*)&ring[0][0][0];    // 5440*4 B fits in ring
  for (int idx = tid; idx < 5440; idx += 256) sJ[idx] = 0.f;
  __syncthreads();
#pragma unroll
  for (int ww = 0; ww < 4; ++ww) {
    if (w == ww) {
#pragma unroll
      for (int nt = 0; nt < 5; ++nt)
#pragma unroll
        for (int ct = 0; ct < 5; ++ct) {
          if (ct < 4 || i < 4) {
            const int col = 16 * ct + i;
#pragma unroll
            for (int rr = 0; rr < 4; ++rr)
              sJ[(16 * nt + 4 * g + rr) * 68 + col] += acc2[nt][ct][rr];
          }
        }
    }
    __syncthreads();
  }
  if (part) {
    for (int idx = tid; idx < 5440; idx += 256)
      part[(size_t)blockIdx.x * 5440 + idx] = sJ[idx];
  } else {
    for (int idx = tid; idx < 5440; idx += 256)
      atomicAdd(&jacc[idx], sJ[idx]);
  }
}

// ---------------------------------------------------------------------------
// kR: jacc[t] += sum over GRID_A block partials (16 slices x 16)
// ---------------------------------------------------------------------------
__global__ __launch_bounds__(256) void kR(const float* __restrict__ part,
                                          float* __restrict__ jacc)
{
  const int bx = blockIdx.x;
  const int cg = bx % 22, sl = bx / 22;
  const int t = cg * 256 + threadIdx.x;
  if (t >= 5440) return;
  const int b0 = sl * (GRID_A / 16);
  float s0 = 0.f, s1 = 0.f, s2 = 0.f, s3 = 0.f;
  for (int b = b0; b < b0 + GRID_A / 16; b += 4) {
    s0 += part[(size_t)(b + 0) * 5440 + t];
    s1 += part[(size_t)(b + 1) * 5440 + t];
    s2 += part[(size_t)(b + 2) * 5440 + t];
    s3 += part[(size_t)(b + 3) * 5440 + t];
  }
  atomicAdd(&jacc[t], (s0 + s1) + (s2 + s3));
}

// ---------------------------------------------------------------------------
// kB: one block (1 wave) per joint: finalize, lo/hi, argmin, full MLP chain
// ---------------------------------------------------------------------------
__global__ __launch_bounds__(64) void kB(
    const float* __restrict__ jacc, const float* __restrict__ smpl,
    const float* __restrict__ sw, const float* __restrict__ bpf,
    const float* __restrict__ w_body, const float* __restrict__ b_body,
    const float* __restrict__ w_pos1, const float* __restrict__ b_pos1,
    const float* __restrict__ w_pos2, const float* __restrict__ b_pos2,
    const float* __restrict__ w_rot,  const float* __restrict__ b_rot,
    const float* __restrict__ w_trans,const float* __restrict__ b_trans,
    float* __restrict__ jpack, float* __restrict__ qpack,
    float* __restrict__ tpack)
{
  const int k = blockIdx.x;
  const int l = threadIdx.x;
  __shared__ float gin[128];
  __shared__ float in2[67];
  __shared__ float h2[128];
  __shared__ float g2[64];
  __shared__ float q7[8];

  const float cnt = jacc[k*68 + 67] + 1e-6f;
  gin[64 + l] = jacc[k*68 + l] / cnt;
  const float jx = jacc[k*68 + 64] / cnt;
  const float jy = jacc[k*68 + 65] / cnt;
  const float jz = jacc[k*68 + 66] / cnt;

  float lo0 = 1e30f, lo1 = 1e30f, lo2 = 1e30f;
  float hi0 = -1e30f, hi1 = -1e30f, hi2 = -1e30f;
  float best = 1e30f; int bi = 0;
  for (int v = l; v < VN; v += 64) {
    float x = smpl[v*3], y = smpl[v*3+1], z = smpl[v*3+2];
    lo0 = fminf(lo0, x); hi0 = fmaxf(hi0, x);
    lo1 = fminf(lo1, y); hi1 = fmaxf(hi1, y);
    lo2 = fminf(lo2, z); hi2 = fmaxf(hi2, z);
    float dx = x - jx, dy = y - jy, dz = z - jz;
    float d = dx*dx + dy*dy + dz*dz;
    if (d < best) { best = d; bi = v; }
  }
#pragma unroll
  for (int m = 1; m < 64; m <<= 1) {
    lo0 = fminf(lo0, __shfl_xor(lo0, m));
    lo1 = fminf(lo1, __shfl_xor(lo1, m));
    lo2 = fminf(lo2, __shfl_xor(lo2, m));
    hi0 = fmaxf(hi0, __shfl_xor(hi0, m));
    hi1 = fmaxf(hi1, __shfl_xor(hi1, m));
    hi2 = fmaxf(hi2, __shfl_xor(hi2, m));
    float d2 = __shfl_xor(best, m); int i2 = __shfl_xor(bi, m);
    if (d2 < best || (d2 == best && i2 < bi)) { best = d2; bi = i2; }
  }

  {
    float s = 0.f;
    for (int j = 0; j < 24; ++j) s += sw[bi*24 + j] * bpf[j*64 + l];
    gin[l] = s;
  }
  if (l < 3) {
    float lo = (l == 0) ? lo0 : (l == 1) ? lo1 : lo2;
    float hi = (l == 0) ? hi0 : (l == 1) ? hi1 : hi2;
    float jc = (l == 0) ? jx : (l == 1) ? jy : jz;
    in2[l] = 2.f * (jc - lo) / (hi - lo + 1e-6f) - 1.f;
  }
  __syncthreads();

  {
    float s = b_body[l];
    for (int t = 0; t < 128; ++t) s += gin[t] * w_body[t*64 + l];
    float u = 0.7978845608028654f * (s + 0.044715f * s * s * s);
    float e = __expf(2.f * u);
    float th = 1.f - 2.f / (e + 1.f);
    in2[3 + l] = 0.5f * s * (1.f + th);
  }
  __syncthreads();

#pragma unroll
  for (int half = 0; half < 2; ++half) {
    const int m = l + 64*half;
    float s = b_pos1[m];
    for (int t = 0; t < 67; ++t) s += in2[t] * w_pos1[t*128 + m];
    h2[m] = fmaxf(s, 0.f);
  }
  __syncthreads();

  {
    float s = b_pos2[l];
    for (int t = 0; t < 128; ++t) s += h2[t] * w_pos2[t*64 + l];
    g2[l] = s;
  }
  __syncthreads();

  if (l < 4) {
    float s = b_rot[l];
    for (int t = 0; t < 64; ++t) s += g2[t] * w_rot[t*4 + l];
    q7[l] = s;
  } else if (l < 7) {
    const int j = l - 4;
    float s = b_trans[j];
    for (int t = 0; t < 64; ++t) s += g2[t] * w_trans[t*3 + j];
    q7[l] = s;
  }
  __syncthreads();
  if (l == 0) {
    float q0 = q7[0], q1 = q7[1], q2 = q7[2], q3 = q7[3];
    float rn = 1.f / (sqrtf(q0*q0 + q1*q1 + q2*q2 + q3*q3) + 1e-6f);
    *(float4*)&qpack[k*4] = make_float4(q0*rn, q1*rn, q2*rn, q3*rn);
    *(float4*)&tpack[k*4] = make_float4(q7[4], q7[5], q7[6], 0.f);
    *(float4*)&jpack[k*4] = make_float4(jx, jy, jz, jx*jx + jy*jy + jz*jz);
  }
}

// ---------------------------------------------------------------------------
// kC: per-point joint softmax + quaternion blend; xyz/out staged via LDS
// ---------------------------------------------------------------------------
__global__ __launch_bounds__(256) void kC(
    const float* __restrict__ xyz, const float* __restrict__ jpack,
    const float* __restrict__ qpack, const float* __restrict__ tpack,
    float* __restrict__ out)
{
  __shared__ float4 sj[NJ], sq[NJ], st[NJ];
  __shared__ float sxy[768];
  const int tid = threadIdx.x;
  const int pbase = blockIdx.x * 256;
  const int nval = min(256, N_PTS - pbase);
  const int cnt3 = nval * 3;

  if (tid < 80)        sj[tid]       = ((const float4*)jpack)[tid];
  else if (tid < 160)  sq[tid - 80]  = ((const float4*)qpack)[tid - 80];
  else if (tid < 240)  st[tid - 160] = ((const float4*)tpack)[tid - 160];
  for (int t = tid; t < cnt3; t += 256) sxy[t] = xyz[(size_t)pbase * 3 + t];
  __syncthreads();

  const bool valid = tid < nval;
  float x0 = 0.f, x1 = 0.f, x2 = 0.f;
  if (valid) { x0 = sxy[tid*3]; x1 = sxy[tid*3+1]; x2 = sxy[tid*3+2]; }
  __syncthreads();

  float lv[NJ];
  float m = -1e30f;
#pragma unroll
  for (int k = 0; k < NJ; ++k) {
    float4 j = sj[k];
    lv[k] = (2.f*(x0*j.x + x1*j.y + x2*j.z) - j.w) * 10.0f;  // 1/SIGMA
    m = fmaxf(m, lv[k]);
  }
  float s = 0.f;
  float qb0=0,qb1=0,qb2=0,qb3=0, tb0=0,tb1=0,tb2=0;
#pragma unroll
  for (int k = 0; k < NJ; ++k) {
    float e = __expf(lv[k] - m);
    s += e;
    float4 q = sq[k];
    float4 t = st[k];
    qb0 += e*q.x; qb1 += e*q.y; qb2 += e*q.z; qb3 += e*q.w;
    tb0 += e*t.x; tb1 += e*t.y; tb2 += e*t.z;
  }
  float rs = 1.f / s;
  qb0*=rs; qb1*=rs; qb2*=rs; qb3*=rs; tb0*=rs; tb1*=rs; tb2*=rs;
  float nrm = sqrtf(qb0*qb0+qb1*qb1+qb2*qb2+qb3*qb3) + 1e-6f;
  float rn = 1.f / nrm;
  float qw = qb0*rn, qx = qb1*rn, qy = qb2*rn, qz = qb3*rn;
  float t2x = 2.f*(qy*x2 - qz*x1);
  float t2y = 2.f*(qz*x0 - qx*x2);
  float t2z = 2.f*(qx*x1 - qy*x0);
  float cx = qy*t2z - qz*t2y;
  float cy = qz*t2x - qx*t2z;
  float cz = qx*t2y - qy*t2x;
  float r0 = x0 + qw*t2x + cx + tb0;
  float r1 = x1 + qw*t2y + cy + tb1;
  float r2 = x2 + qw*t2z + cz + tb2;

  if (valid) { sxy[tid*3] = r0; sxy[tid*3+1] = r1; sxy[tid*3+2] = r2; }
  __syncthreads();
  for (int t = tid; t < cnt3; t += 256) out[(size_t)pbase * 3 + t] = sxy[t];
}

// ---------------------------------------------------------------------------
extern "C" void kernel_launch(void* const* d_in, const int* in_sizes, int n_in,
                              void* d_out, int out_size, void* d_ws, size_t ws_size,
                              hipStream_t stream) {
  const float* xyz     = (const float*)d_in[0];
  const float* feature = (const float*)d_in[1];
  const float* centers = (const float*)d_in[2];
  const float* smpl    = (const float*)d_in[3];
  const float* sw      = (const float*)d_in[4];
  const float* bpf     = (const float*)d_in[5];
  const float* w_body  = (const float*)d_in[6];
  const float* b_body  = (const float*)d_in[7];
  const float* w_pos1  = (const float*)d_in[8];
  const float* b_pos1  = (const float*)d_in[9];
  const float* w_pos2  = (const float*)d_in[10];
  const float* b_pos2  = (const float*)d_in[11];
  const float* w_rot   = (const float*)d_in[12];
  const float* b_rot   = (const float*)d_in[13];
  const float* w_trans = (const float*)d_in[14];
  const float* b_trans = (const float*)d_in[15];
  float* out = (float*)d_out;

  float* ws    = (float*)d_ws;
  float* jacc  = ws;                  // 5440
  float* jpack = ws + 5440;           // 320
  float* qpack = ws + 5760;           // 320
  float* tpack = ws + 6080;           // 320
  float* part  = ws + 6400;           // GRID_A * 5440 (if it fits)

  const size_t need = (size_t)6400 + (size_t)GRID_A * 5440;
  const bool use_part = (ws_size / 4) >= need;
  float* part_arg = use_part ? part : nullptr;

  hipMemsetAsync(jacc, 0, 5440 * sizeof(float), stream);
  kA<<<dim3(GRID_A), dim3(256), 0, stream>>>(xyz, feature, centers, jacc, part_arg);
  if (use_part)
    kR<<<dim3(22 * 16), dim3(256), 0, stream>>>(part, jacc);
  kB<<<dim3(NJ), dim3(64), 0, stream>>>(jacc, smpl, sw, bpf,
                                        w_body, b_body, w_pos1, b_pos1,
                                        w_pos2, b_pos2, w_rot, b_rot,
                                        w_trans, b_trans, jpack, qpack, tpack);
  kC<<<dim3((N_PTS + 255) / 256), dim3(256), 0, stream>>>(xyz, jpack, qpack, tpack, out);
}